// Round 10
// baseline (538.546 us; speedup 1.0000x reference)
//
#include <hip/hip_runtime.h>

#define NB 2048
#define NT 2048
#define NH 16

#define OFF_IMP   1L
#define OFF_TRAIN (1L + (long)NB * NT)
#define OFF_EVALS (OFF_TRAIN + NB)
#define OFF_EMASK (OFF_EVALS + (long)NB * NT)

// ws layout: num_t[NT] | den_t[NT] | amt[NB*NT] (path A)  or  rep[NREP*NT] (path B)
#define WS_AMT_OFF 4096
#define NREP 64

typedef float f2 __attribute__((ext_vector_type(2)));

// ---------------- copies + workspace zeroing ----------------
__global__ void copy_zero_kernel(const float* __restrict__ evals,
                                 const float* __restrict__ emask,
                                 const float* __restrict__ is_train,
                                 float* __restrict__ out,
                                 float* __restrict__ ws,
                                 int n_zero) {
    long gid = (long)blockIdx.x * blockDim.x + threadIdx.x;
    if (gid < n_zero) ws[gid] = 0.0f;
    const long n1 = (long)NB * NT;
    const long total = NB + 2 * n1;
    const long stride = (long)gridDim.x * blockDim.x;
    for (long i = gid; i < total; i += stride) {
        if (i < NB)            out[OFF_TRAIN + i] = is_train[i];
        else if (i < NB + n1)  out[OFF_EVALS + (i - NB)] = evals[i - NB];
        else                   out[OFF_EMASK + (i - NB - n1)] = emask[i - NB - n1];
    }
}

// ---------------- LSTM scan: 16 lanes = 1 batch, 4 batches per wave --------
// R9 structure (verified, absmax 0.0078): lane (g,j) owns unit j of batch g,
// computes all 4 gate rows locally; h broadcast = 1 ds_write + 4 ds_read_b128
// per lane in the group's private LDS row (same-wave DS order, no barrier).
// R10 edits: (a) weights pinned in VGPRs via opaque asm — forbids the
// compiler's per-step reload-from-global; (b) gate preacts take xh directly
// (m∈{0,1} exact), moving all m/x terms off the recurrence chain; (c) the
// five 16-dots interleaved as 10 round-robin chains (within-dot association
// bit-frozen from R9); (d) xc/av/store math placed after the DS ops to fill
// the LDS-latency shadow.

#define L2E 1.4426950408889634f

#define DOTSTAGE(K)                                                            \
    aI = __builtin_elementwise_fma(H2[K], WI[K], aI);                          \
    aF = __builtin_elementwise_fma(H2[K], WF[K], aF);                          \
    aG = __builtin_elementwise_fma(H2[K], WG[K], aG);                          \
    aO = __builtin_elementwise_fma(H2[K], WO[K], aO);                          \
    aR = __builtin_elementwise_fma(H2[K], WR[K], aR);                          \
    bI = __builtin_elementwise_fma(H2[K + 4], WI[K + 4], bI);                  \
    bF = __builtin_elementwise_fma(H2[K + 4], WF[K + 4], bF);                  \
    bG = __builtin_elementwise_fma(H2[K + 4], WG[K + 4], bG);                  \
    bO = __builtin_elementwise_fma(H2[K + 4], WO[K + 4], bO);                  \
    bR = __builtin_elementwise_fma(H2[K + 4], WR[K + 4], bR);

#define STEP(xx, mm, XI, AI) do {                                              \
    f2 aI = H2[0] * WI[0], bI = H2[4] * WI[4];                                 \
    f2 aF = H2[0] * WF[0], bF = H2[4] * WF[4];                                 \
    f2 aG = H2[0] * WG[0], bG = H2[4] * WG[4];                                 \
    f2 aO = H2[0] * WO[0], bO = H2[4] * WO[4];                                 \
    f2 aR = H2[0] * WR[0], bR = H2[4] * WR[4];                                 \
    DOTSTAGE(1) DOTSTAGE(2) DOTSTAGE(3)                                        \
    const float gI = (aI.x + aI.y) + (bI.x + bI.y);                            \
    const float gF = (aF.x + aF.y) + (bF.x + bF.y);                            \
    const float gG = (aG.x + aG.y) + (bG.x + bG.y);                            \
    const float gO = (aO.x + aO.y) + (bO.x + bO.y);                            \
    const float xh = brg + ((aR.x + aR.y) + (bR.x + bR.y));                    \
    /* off-chain prep (only x,m): pk over gate pairs (I,F) and (G,O) */        \
    const f2 m2 = (f2){(mm), (mm)};                                            \
    const f2 x2 = (f2){(xx), (xx)};                                            \
    const f2 preIF = __builtin_elementwise_fma(wx1IF, m2, bIF);                \
    const f2 preGO = __builtin_elementwise_fma(wx1GO, m2, bGO);                \
    const f2 uIF = wx0IF * m2;                                                 \
    const f2 uGO = wx0GO * m2;                                                 \
    const f2 eIF = wx0IF - uIF;                                                \
    const f2 eGO = wx0GO - uGO;                                                \
    const f2 b0IF = __builtin_elementwise_fma(uIF, x2, preIF);                 \
    const f2 b0GO = __builtin_elementwise_fma(uGO, x2, preGO);                 \
    /* on-chain: one fma from xh per gate */                                   \
    const float pI = fmaf(eIF.x, xh, gI + b0IF.x);                             \
    const float pF = fmaf(eIF.y, xh, gF + b0IF.y);                             \
    const float pG = fmaf(eGO.x, xh, gG + b0GO.x);                             \
    const float pO = fmaf(eGO.y, xh, gO + b0GO.y);                             \
    const float aIv = __builtin_amdgcn_rcpf(1.0f + __builtin_amdgcn_exp2f(pI * (-L2E)));  \
    const float aFv = __builtin_amdgcn_rcpf(1.0f + __builtin_amdgcn_exp2f(pF * (-L2E)));  \
    const float aGv = fmaf(2.0f, __builtin_amdgcn_rcpf(1.0f + __builtin_amdgcn_exp2f(pG * (-2.0f * L2E))), -1.0f); \
    const float aOv = __builtin_amdgcn_rcpf(1.0f + __builtin_amdgcn_exp2f(pO * (-L2E)));  \
    c = fmaf(aFv, c, aIv * aGv);                                               \
    const float th = fmaf(2.0f, __builtin_amdgcn_rcpf(1.0f + __builtin_amdgcn_exp2f(c * (-2.0f * L2E))), -1.0f); \
    const float ht = aOv * th;                                                 \
    hsh[hpos] = ht;                                                            \
    {                                                                          \
        const float4 h0_ = *(const float4*)(hsh + (g << 4) + 0);               \
        const float4 h1_ = *(const float4*)(hsh + (g << 4) + 4);               \
        const float4 h2_ = *(const float4*)(hsh + (g << 4) + 8);               \
        const float4 h3_ = *(const float4*)(hsh + (g << 4) + 12);              \
        H2[0] = (f2){h0_.x, h0_.y}; H2[1] = (f2){h0_.z, h0_.w};                \
        H2[2] = (f2){h1_.x, h1_.y}; H2[3] = (f2){h1_.z, h1_.w};                \
        H2[4] = (f2){h2_.x, h2_.y}; H2[5] = (f2){h2_.z, h2_.w};                \
        H2[6] = (f2){h3_.x, h3_.y}; H2[7] = (f2){h3_.z, h3_.w};                \
    }                                                                          \
    /* off-chain epilogue in the DS-latency shadow */                          \
    const float dxm = (xx) - xh;                                               \
    XI = fmaf((mm), dxm, xh);                                                  \
    AI = fabsf(dxm) * (mm);                                                    \
} while (0)

#define QUAD(XV, MV, T4) do {                                                  \
    float xi0, xi1, xi2, xi3, ai0, ai1, ai2, ai3;                              \
    STEP(XV.x, MV.x, xi0, ai0); STEP(XV.y, MV.y, xi1, ai1);                    \
    STEP(XV.z, MV.z, xi2, ai2); STEP(XV.w, MV.w, xi3, ai3);                    \
    if (ATOMIC) {                                                              \
        if (j == 0) {                                                          \
            atomicAdd(ab + (T4) + 0, ai0); atomicAdd(ab + (T4) + 1, ai1);      \
            atomicAdd(ab + (T4) + 2, ai2); atomicAdd(ab + (T4) + 3, ai3);      \
        }                                                                      \
        if (j < 4) {                                                           \
            const float sx = (j == 1) ? xi1 : (j == 2) ? xi2 : (j == 3) ? xi3 : xi0; \
            ib[(T4) + j] = sx;                                                 \
        }                                                                      \
    } else {                                                                   \
        const int jq = j & 3;                                                  \
        const float sx = (jq == 1) ? xi1 : (jq == 2) ? xi2 : (jq == 3) ? xi3 : xi0; \
        const float sa = (jq == 1) ? ai1 : (jq == 2) ? ai2 : (jq == 3) ? ai3 : ai0; \
        if (j < 8) pst[T4] = (j < 4) ? sx : sa;                                \
    }                                                                          \
} while (0)

template <int ATOMIC>
__global__ __launch_bounds__(64, 1)
void lstm_kernel(const float* __restrict__ values,
                 const float* __restrict__ masks,
                 const float* __restrict__ W_ih,
                 const float* __restrict__ W_hh,
                 const float* __restrict__ b_ih,
                 const float* __restrict__ b_hh,
                 const float* __restrict__ W_reg,
                 const float* __restrict__ b_reg,
                 float* __restrict__ imp,   // out + OFF_IMP
                 float* __restrict__ amt) { // A: amt[NB*NT]; B: rep[NREP*NT]
    const int lane = threadIdx.x;          // 0..63
    const int g = lane >> 4;               // batch slot within wave
    const int j = lane & 15;               // hidden unit
    const long b = (long)blockIdx.x * 4 + g;

    // Per-lane weights: all 4 W_hh gate rows for unit j + W_reg, packed as
    // f2 pairs (w_k, w_{k+4}) matching the permuted LDS h layout.
    f2 WI[8], WF[8], WG[8], WO[8], WR[8];
    {
        const float* rI = W_hh + (0 * NH + j) * NH;
        const float* rF = W_hh + (1 * NH + j) * NH;
        const float* rG = W_hh + (2 * NH + j) * NH;
        const float* rO = W_hh + (3 * NH + j) * NH;
#pragma unroll
        for (int k = 0; k < 4; ++k) {
            WI[k] = (f2){rI[k], rI[k + 4]};  WI[4 + k] = (f2){rI[8 + k], rI[12 + k]};
            WF[k] = (f2){rF[k], rF[k + 4]};  WF[4 + k] = (f2){rF[8 + k], rF[12 + k]};
            WG[k] = (f2){rG[k], rG[k + 4]};  WG[4 + k] = (f2){rG[8 + k], rG[12 + k]};
            WO[k] = (f2){rO[k], rO[k + 4]};  WO[4 + k] = (f2){rO[8 + k], rO[12 + k]};
            WR[k] = (f2){W_reg[k], W_reg[k + 4]};
            WR[4 + k] = (f2){W_reg[8 + k], W_reg[12 + k]};
        }
    }
    // Pin all weights in VGPRs: opaque asm forbids re-deriving them from
    // memory inside the loop (R9's VGPR=80 showed the compiler was
    // re-loading weights per step instead of keeping them resident).
#pragma unroll
    for (int k = 0; k < 8; ++k) {
        asm volatile("" : "+v"(WI[k]), "+v"(WF[k]), "+v"(WG[k]), "+v"(WO[k]), "+v"(WR[k]));
    }

    const f2 wx0IF = (f2){W_ih[(0 * NH + j) * 2 + 0], W_ih[(1 * NH + j) * 2 + 0]};
    const f2 wx0GO = (f2){W_ih[(2 * NH + j) * 2 + 0], W_ih[(3 * NH + j) * 2 + 0]};
    const f2 wx1IF = (f2){W_ih[(0 * NH + j) * 2 + 1], W_ih[(1 * NH + j) * 2 + 1]};
    const f2 wx1GO = (f2){W_ih[(2 * NH + j) * 2 + 1], W_ih[(3 * NH + j) * 2 + 1]};
    const f2 bIF = (f2){b_ih[0 * NH + j] + b_hh[0 * NH + j],
                        b_ih[1 * NH + j] + b_hh[1 * NH + j]};
    const f2 bGO = (f2){b_ih[2 * NH + j] + b_hh[2 * NH + j],
                        b_ih[3 * NH + j] + b_hh[3 * NH + j]};
    const float brg = b_reg[0];

    f2 H2[8];
#pragma unroll
    for (int k = 0; k < 8; ++k) H2[k] = (f2){0.0f, 0.0f};
    float c = 0.0f;

    // Permuted h store position: layout [h0,h4,h1,h5,h2,h6,h3,h7, h8,h12,...]
    __shared__ __align__(16) float hsh[64];
    const int jj = j & 7;
    const int hpos = (g << 4) + ((j >> 3) << 3) + ((jj & 3) << 1) + (jj >> 2);

    const float* vb = values + b * NT;
    const float* mb = masks + b * NT;
    float* ib = imp + b * NT;
    float* ab = ATOMIC ? (amt + (long)(b & (NREP - 1)) * NT) : (amt + b * NT);
    // lanes j=0..3 -> imputation col jq, lanes j=4..7 -> loss col jq
    float* pst = ((j < 4) ? ib : ab) + (j & 3);

    // 4 static prefetch buffers, 16-step unrolled body
    float4 xA = *(const float4*)(vb + 0),  mA = *(const float4*)(mb + 0);
    float4 xB = *(const float4*)(vb + 4),  mB = *(const float4*)(mb + 4);
    float4 xC = *(const float4*)(vb + 8),  mC = *(const float4*)(mb + 8);
    float4 xD = *(const float4*)(vb + 12), mD = *(const float4*)(mb + 12);

    for (int t = 0; t < NT; t += 16) {
        QUAD(xA, mA, t + 0);
        QUAD(xB, mB, t + 4);
        {
            const int tn = (t + 16) & (NT - 1);  // wraps harmlessly on last iter
            xA = *(const float4*)(vb + tn);      mA = *(const float4*)(mb + tn);
            xB = *(const float4*)(vb + tn + 4);  mB = *(const float4*)(mb + tn + 4);
        }
        QUAD(xC, mC, t + 8);
        QUAD(xD, mD, t + 12);
        {
            const int tn = (t + 24) & (NT - 1);
            xC = *(const float4*)(vb + tn);      mC = *(const float4*)(mb + tn);
            xD = *(const float4*)(vb + tn + 4);  mD = *(const float4*)(mb + tn + 4);
        }
    }
}

// ---------------- column-sum reduce: num_t / den_t ----------------
template <int ATOMIC>
__global__ void reduce_kernel(const float* __restrict__ masks,
                              const float* __restrict__ amt,
                              float* __restrict__ num_t,
                              float* __restrict__ den_t) {
    const int t = blockIdx.x * 256 + threadIdx.x;
    const int b0 = blockIdx.y * 32;
    float sd = 0.0f;
    for (int bb = b0; bb < b0 + 32; ++bb) sd += masks[(long)bb * NT + t];
    atomicAdd(den_t + t, sd);
    if (!ATOMIC) {
        float sn = 0.0f;
        for (int bb = b0; bb < b0 + 32; ++bb) sn += amt[(long)bb * NT + t];
        atomicAdd(num_t + t, sn);
    } else if (blockIdx.y == 0) {
        float sn = 0.0f;
        for (int r = 0; r < NREP; ++r) sn += amt[(long)r * NT + t];
        num_t[t] = sn;  // single writer
    }
}

// ---------------- loss finalize ----------------
__global__ void loss_kernel(const float* __restrict__ num_t, const float* __restrict__ den_t,
                            float* __restrict__ out) {
    const int tid = threadIdx.x;
    float s = 0.0f;
    for (int t = tid; t < NT; t += 256) s += num_t[t] / (den_t[t] + 1e-5f);
#pragma unroll
    for (int off = 32; off > 0; off >>= 1) s += __shfl_down(s, off, 64);
    __shared__ float red[4];
    if ((tid & 63) == 0) red[tid >> 6] = s;
    __syncthreads();
    if (tid == 0) out[0] = (red[0] + red[1] + red[2] + red[3]) / (float)NT;
}

extern "C" void kernel_launch(void* const* d_in, const int* in_sizes, int n_in,
                              void* d_out, int out_size, void* d_ws, size_t ws_size,
                              hipStream_t stream) {
    const float* values  = (const float*)d_in[0];
    const float* masks   = (const float*)d_in[1];
    const float* evals   = (const float*)d_in[2];
    const float* emask   = (const float*)d_in[3];
    const float* istrain = (const float*)d_in[4];
    const float* W_ih    = (const float*)d_in[5];
    const float* W_hh    = (const float*)d_in[6];
    const float* b_ih    = (const float*)d_in[7];
    const float* b_hh    = (const float*)d_in[8];
    const float* W_reg   = (const float*)d_in[9];
    const float* b_reg   = (const float*)d_in[10];

    float* out = (float*)d_out;
    float* ws = (float*)d_ws;
    float* num_t = ws;
    float* den_t = ws + NT;
    float* amt = ws + WS_AMT_OFF;

    const bool pathA = ws_size >= (size_t)(WS_AMT_OFF + (long)NB * NT) * 4;

    if (pathA) {
        copy_zero_kernel<<<1024, 256, 0, stream>>>(evals, emask, istrain, out, ws, WS_AMT_OFF);
        lstm_kernel<0><<<NB / 4, 64, 0, stream>>>(values, masks, W_ih, W_hh, b_ih, b_hh,
                                                  W_reg, b_reg, out + OFF_IMP, amt);
        reduce_kernel<0><<<dim3(NT / 256, 64), 256, 0, stream>>>(masks, amt, num_t, den_t);
    } else {
        copy_zero_kernel<<<1024, 256, 0, stream>>>(evals, emask, istrain, out, ws,
                                                   WS_AMT_OFF + NREP * NT);
        lstm_kernel<1><<<NB / 4, 64, 0, stream>>>(values, masks, W_ih, W_hh, b_ih, b_hh,
                                                  W_reg, b_reg, out + OFF_IMP, amt);
        reduce_kernel<1><<<dim3(NT / 256, 64), 256, 0, stream>>>(masks, amt, num_t, den_t);
    }
    loss_kernel<<<1, 256, 0, stream>>>(num_t, den_t, out);
}